// Round 1
// baseline (406.120 us; speedup 1.0000x reference)
//
#include <hip/hip_runtime.h>
#include <hip/hip_bf16.h>
#include <math.h>

#define EPSF 1e-8f
typedef __hip_bfloat16 bf16;

__device__ __forceinline__ float wred_sum(float v) {
#pragma unroll
  for (int o = 32; o > 0; o >>= 1) v += __shfl_down(v, o, 64);
  return v;
}
__device__ __forceinline__ float wred_max(float v) {
#pragma unroll
  for (int o = 32; o > 0; o >>= 1) v = fmaxf(v, __shfl_down(v, o, 64));
  return v;
}

// ---------------- K1: per-(b,c) masked mean/std over T ----------------
__global__ __launch_bounds__(256) void k_meanstd(
    const float* __restrict__ x, const int* __restrict__ mask,
    float* __restrict__ mean, float* __restrict__ stdv, int C, int T) {
  int bc = blockIdx.x;
  int b = bc / C;
  const float* xr = x + (size_t)bc * T;
  const int* mr = mask + (size_t)b * T;
  float s1 = 0.f, s2 = 0.f, sl = 0.f;
  for (int t = threadIdx.x; t < T; t += 256) {
    float m = (float)mr[t];
    float v = xr[t];
    s1 += m * v;
    s2 += m * v * v;
    sl += m;
  }
  __shared__ float r1[4], r2[4], rl[4];
  s1 = wred_sum(s1); s2 = wred_sum(s2); sl = wred_sum(sl);
  int w = threadIdx.x >> 6;
  if ((threadIdx.x & 63) == 0) { r1[w] = s1; r2[w] = s2; rl[w] = sl; }
  __syncthreads();
  if (threadIdx.x == 0) {
    s1 = r1[0] + r1[1] + r1[2] + r1[3];
    s2 = r2[0] + r2[1] + r2[2] + r2[3];
    sl = rl[0] + rl[1] + rl[2] + rl[3];
    float L = fmaxf(sl, 1.f);
    float mu = s1 / L;
    float var = s2 / L - mu * mu;
    mean[bc] = mu;
    stdv[bc] = sqrtf(fmaxf(var, EPSF));
  }
}

// ---------------- K2: bias2[b,d] = attn_b[d] + w[d,C:2C].mean + w[d,2C:3C].std
__global__ __launch_bounds__(256) void k_bias2(
    const float* __restrict__ attn_w, const float* __restrict__ attn_b,
    const float* __restrict__ mean, const float* __restrict__ stdv,
    float* __restrict__ bias2, int C, int D) {
  int bd = blockIdx.x;
  int b = bd / D;
  int d = bd % D;
  const float* wr = attn_w + (size_t)d * 3 * C;
  float s = 0.f;
  for (int c = threadIdx.x; c < C; c += 256)
    s += wr[C + c] * mean[(size_t)b * C + c] + wr[2 * C + c] * stdv[(size_t)b * C + c];
  __shared__ float r[4];
  s = wred_sum(s);
  if ((threadIdx.x & 63) == 0) r[threadIdx.x >> 6] = s;
  __syncthreads();
  if (threadIdx.x == 0) bias2[bd] = attn_b[d] + r[0] + r[1] + r[2] + r[3];
}

// ---------------- K3: alpha[b,d,t] = tanh(bias2[b,d] + sum_c attn_w[d,c]*x[b,c,t])
// Tile: 128 d x 128 t, K-chunks of 32. 256 threads, 8x8 micro-tile.
#define G1BK 32
__global__ __launch_bounds__(256) void k_gemm1(
    const float* __restrict__ x, const float* __restrict__ attn_w,
    const float* __restrict__ bias2, bf16* __restrict__ alpha,
    int C, int T, int D, int C3) {
  int b = blockIdx.y;
  int t0 = blockIdx.x * 128;
  __shared__ float As[G1BK][132];  // [k][d], padded
  __shared__ float Bs[G1BK][132];  // [k][t], padded
  int tid = threadIdx.x;
  int ty = tid >> 4, tx = tid & 15;
  float acc[8][8];
#pragma unroll
  for (int i = 0; i < 8; i++)
#pragma unroll
    for (int j = 0; j < 8; j++) acc[i][j] = 0.f;

  int lk = tid & 31;
  int ld0 = (tid >> 5) * 16;
  int ltt = tid & 127;
  int lk0 = tid >> 7;
  const float* xb = x + (size_t)b * C * T;

  for (int c0 = 0; c0 < C; c0 += G1BK) {
    __syncthreads();
#pragma unroll
    for (int i = 0; i < 16; i++)
      As[lk][ld0 + i] = attn_w[(size_t)(ld0 + i) * C3 + c0 + lk];
    int t = t0 + ltt;
#pragma unroll
    for (int j = 0; j < 16; j++) {
      int k = lk0 + j * 2;
      Bs[k][ltt] = (t < T) ? xb[(size_t)(c0 + k) * T + t] : 0.f;
    }
    __syncthreads();
#pragma unroll
    for (int k = 0; k < G1BK; k++) {
      float a[8], bb[8];
#pragma unroll
      for (int i = 0; i < 8; i++) a[i] = As[k][ty * 8 + i];
#pragma unroll
      for (int j = 0; j < 8; j++) bb[j] = Bs[k][tx * 8 + j];
#pragma unroll
      for (int i = 0; i < 8; i++)
#pragma unroll
        for (int j = 0; j < 8; j++) acc[i][j] = fmaf(a[i], bb[j], acc[i][j]);
    }
  }
  bf16* ab = alpha + (size_t)b * D * T;
#pragma unroll
  for (int i = 0; i < 8; i++) {
    int d = ty * 8 + i;
    float bias = bias2[(size_t)b * D + d];
#pragma unroll
    for (int j = 0; j < 8; j++) {
      int t = t0 + tx * 8 + j;
      if (t < T) ab[(size_t)d * T + t] = __float2bfloat16(tanhf(bias + acc[i][j]));
    }
  }
}

// ---------------- K4: alpha2[b,c,t] = ctx_b[c] + sum_d ctx_w[c,d]*alpha[b,d,t]
// Tile: 64 c x 128 t, K-chunks of 32. 256 threads, 4x8 micro-tile.
__global__ __launch_bounds__(256) void k_gemm2(
    const bf16* __restrict__ alpha, const float* __restrict__ ctx_w,
    const float* __restrict__ ctx_b, bf16* __restrict__ alpha2,
    int C, int T, int D) {
  int b = blockIdx.z;
  int c0 = blockIdx.y * 64;
  int t0 = blockIdx.x * 128;
  __shared__ float Ws[G1BK][68];   // [k][c], padded
  __shared__ float Bs[G1BK][132];  // [k][t], padded
  int tid = threadIdx.x;
  int ty = tid >> 4, tx = tid & 15;
  float acc[4][8];
#pragma unroll
  for (int i = 0; i < 4; i++)
#pragma unroll
    for (int j = 0; j < 8; j++) acc[i][j] = 0.f;

  int ld = tid & 31;
  int lc0 = (tid >> 5) * 8;
  int ltt = tid & 127;
  int lk0 = tid >> 7;
  const bf16* ab = alpha + (size_t)b * D * T;

  for (int d0 = 0; d0 < D; d0 += G1BK) {
    __syncthreads();
#pragma unroll
    for (int i = 0; i < 8; i++)
      Ws[ld][lc0 + i] = ctx_w[(size_t)(c0 + lc0 + i) * D + d0 + ld];
    int t = t0 + ltt;
#pragma unroll
    for (int j = 0; j < 16; j++) {
      int k = lk0 + j * 2;
      Bs[k][ltt] = (t < T) ? __bfloat162float(ab[(size_t)(d0 + k) * T + t]) : 0.f;
    }
    __syncthreads();
#pragma unroll
    for (int k = 0; k < G1BK; k++) {
      float a[4], bb[8];
#pragma unroll
      for (int i = 0; i < 4; i++) a[i] = Ws[k][ty * 4 + i];
#pragma unroll
      for (int j = 0; j < 8; j++) bb[j] = Bs[k][tx * 8 + j];
#pragma unroll
      for (int i = 0; i < 4; i++)
#pragma unroll
        for (int j = 0; j < 8; j++) acc[i][j] = fmaf(a[i], bb[j], acc[i][j]);
    }
  }
#pragma unroll
  for (int i = 0; i < 4; i++) {
    int c = c0 + ty * 4 + i;
    float bias = ctx_b[c];
#pragma unroll
    for (int j = 0; j < 8; j++) {
      int t = t0 + tx * 8 + j;
      if (t < T)
        alpha2[((size_t)b * C + c) * T + t] = __float2bfloat16(bias + acc[i][j]);
    }
  }
}

// ---------------- K5: masked softmax over T + attentive pooled mean/std
__global__ __launch_bounds__(256) void k_pool(
    const float* __restrict__ x, const bf16* __restrict__ alpha2,
    const int* __restrict__ mask, float* __restrict__ out, int C, int T) {
  int bc = blockIdx.x;
  int b = bc / C;
  int c = bc % C;
  const bf16* ar = alpha2 + (size_t)bc * T;
  const float* xr = x + (size_t)bc * T;
  const int* mr = mask + (size_t)b * T;

  float mx = -1e30f;
  for (int t = threadIdx.x; t < T; t += 256)
    if (mr[t]) mx = fmaxf(mx, __bfloat162float(ar[t]));
  __shared__ float rm[4];
  mx = wred_max(mx);
  if ((threadIdx.x & 63) == 0) rm[threadIdx.x >> 6] = mx;
  __syncthreads();
  mx = fmaxf(fmaxf(rm[0], rm[1]), fmaxf(rm[2], rm[3]));

  float s0 = 0.f, s1 = 0.f, s2 = 0.f;
  for (int t = threadIdx.x; t < T; t += 256) {
    if (mr[t]) {
      float e = __expf(__bfloat162float(ar[t]) - mx);
      float v = xr[t];
      s0 += e;
      s1 += e * v;
      s2 += e * v * v;
    }
  }
  __shared__ float q0[4], q1[4], q2[4];
  s0 = wred_sum(s0); s1 = wred_sum(s1); s2 = wred_sum(s2);
  int w = threadIdx.x >> 6;
  if ((threadIdx.x & 63) == 0) { q0[w] = s0; q1[w] = s1; q2[w] = s2; }
  __syncthreads();
  if (threadIdx.x == 0) {
    float S0 = q0[0] + q0[1] + q0[2] + q0[3];
    float S1 = q1[0] + q1[1] + q1[2] + q1[3];
    float S2 = q2[0] + q2[1] + q2[2] + q2[3];
    float pm = S1 / S0;
    float pv = S2 / S0 - pm * pm;
    out[(size_t)b * 2 * C + c] = pm;
    out[(size_t)b * 2 * C + C + c] = sqrtf(fmaxf(pv, EPSF));
  }
}

extern "C" void kernel_launch(void* const* d_in, const int* in_sizes, int n_in,
                              void* d_out, int out_size, void* d_ws, size_t ws_size,
                              hipStream_t stream) {
  const float* x = (const float*)d_in[0];
  const float* attn_w = (const float*)d_in[1];
  const float* attn_b = (const float*)d_in[2];
  const float* ctx_w = (const float*)d_in[3];
  const float* ctx_b = (const float*)d_in[4];
  const int* mask = (const int*)d_in[5];
  float* out = (float*)d_out;

  int D = in_sizes[2];            // 128
  int C = in_sizes[4];            // 512
  int C3 = 3 * C;                 // 1536
  int B = out_size / (2 * C);     // 32
  int T = in_sizes[5] / B;        // 2000

  // workspace layout
  float* mean = (float*)d_ws;                       // B*C
  float* stdv = mean + (size_t)B * C;               // B*C
  float* bias2 = stdv + (size_t)B * C;              // B*D
  bf16* alpha = (bf16*)(bias2 + (size_t)B * D);     // B*D*T
  bf16* alpha2 = alpha + (size_t)B * D * T;         // B*C*T

  k_meanstd<<<B * C, 256, 0, stream>>>(x, mask, mean, stdv, C, T);
  k_bias2<<<B * D, 256, 0, stream>>>(attn_w, attn_b, mean, stdv, bias2, C, D);
  dim3 g3((T + 127) / 128, B);
  k_gemm1<<<g3, 256, 0, stream>>>(x, attn_w, bias2, alpha, C, T, D, C3);
  dim3 g4((T + 127) / 128, C / 64, B);
  k_gemm2<<<g4, 256, 0, stream>>>(alpha, ctx_w, ctx_b, alpha2, C, T, D);
  k_pool<<<B * C, 256, 0, stream>>>(x, alpha2, mask, out, C, T);
}

// Round 2
// 208.351 us; speedup vs baseline: 1.9492x; 1.9492x over previous
//
#include <hip/hip_runtime.h>
#include <hip/hip_bf16.h>
#include <math.h>

#define EPSF 1e-8f
typedef __attribute__((ext_vector_type(8))) short short8;
typedef __attribute__((ext_vector_type(4))) float f32x4;

__device__ __forceinline__ float wred_sum(float v) {
#pragma unroll
  for (int o = 32; o > 0; o >>= 1) v += __shfl_down(v, o, 64);
  return v;
}

static __device__ __forceinline__ unsigned short f2bf(float f) {
  __hip_bfloat16 h = __float2bfloat16(f);
  return *reinterpret_cast<unsigned short*>(&h);
}

// ---------------- K0: weights -> bf16 (awb[d][c] from attn_w[:, :C]; cwb = ctx_w)
__global__ __launch_bounds__(256) void k_convert(
    const float* __restrict__ attn_w, const float* __restrict__ ctx_w,
    unsigned short* __restrict__ awb, unsigned short* __restrict__ cwb, int C, int D) {
  int i = blockIdx.x * 256 + threadIdx.x;
  int DC = D * C;
  if (i < DC) {
    int d = i / C, c = i % C;
    awb[i] = f2bf(attn_w[(size_t)d * 3 * C + c]);
  } else if (i < 2 * DC) {
    int j = i - DC;
    cwb[j] = f2bf(ctx_w[j]);
  }
}

// ---------------- K1: fused masked mean/std + transpose x -> xbT[b][t][c] bf16
__global__ __launch_bounds__(256) void k_ms_tr(
    const float* __restrict__ x, const int* __restrict__ mask,
    float* __restrict__ mean, float* __restrict__ stdv,
    unsigned short* __restrict__ xbT, int C, int T) {
  int b = blockIdx.y, c0 = blockIdx.x * 64;
  int tid = threadIdx.x;
  int row = tid >> 2, q = tid & 3;
  __shared__ float Xs[64][65];
  const float* xr = x + ((size_t)b * C + c0 + row) * T;
  const int* mr = mask + (size_t)b * T;
  float s1 = 0.f, s2 = 0.f, sl = 0.f;

  for (int t0 = 0; t0 < T; t0 += 64) {
#pragma unroll
    for (int ss = 0; ss < 4; ss++) {
      int cc = q + 4 * ss;
      int t = t0 + cc * 4;
      float4 v;
      float mv[4];
      if (t + 3 < T) {
        v = *reinterpret_cast<const float4*>(&xr[t]);
        int4 mm = *reinterpret_cast<const int4*>(&mr[t]);
        mv[0] = (float)mm.x; mv[1] = (float)mm.y; mv[2] = (float)mm.z; mv[3] = (float)mm.w;
      } else {
        v.x = (t < T) ? xr[t] : 0.f;     mv[0] = (t < T) ? (float)mr[t] : 0.f;
        v.y = (t+1 < T) ? xr[t+1] : 0.f; mv[1] = (t+1 < T) ? (float)mr[t+1] : 0.f;
        v.z = (t+2 < T) ? xr[t+2] : 0.f; mv[2] = (t+2 < T) ? (float)mr[t+2] : 0.f;
        v.w = (t+3 < T) ? xr[t+3] : 0.f; mv[3] = (t+3 < T) ? (float)mr[t+3] : 0.f;
      }
      s1 += mv[0]*v.x + mv[1]*v.y + mv[2]*v.z + mv[3]*v.w;
      s2 += mv[0]*v.x*v.x + mv[1]*v.y*v.y + mv[2]*v.z*v.z + mv[3]*v.w*v.w;
      sl += mv[0] + mv[1] + mv[2] + mv[3];
      int tl = cc * 4;
      Xs[row][tl+0] = v.x; Xs[row][tl+1] = v.y; Xs[row][tl+2] = v.z; Xs[row][tl+3] = v.w;
    }
    __syncthreads();
    // transpose write: row trow of xbT gets 64 c's (this thread writes 16)
    int trow = tid >> 2;
    int t = t0 + trow;
    if (t < T) {
      unsigned short buf[16];
#pragma unroll
      for (int m = 0; m < 16; m++) buf[m] = f2bf(Xs[q * 16 + m][trow]);
      unsigned short* dst = &xbT[((size_t)b * T + t) * C + c0 + q * 16];
      *reinterpret_cast<short8*>(dst) = *reinterpret_cast<short8*>(&buf[0]);
      *reinterpret_cast<short8*>(dst + 8) = *reinterpret_cast<short8*>(&buf[8]);
    }
    __syncthreads();
  }
  // reduce the 4 lanes sharing a row
  s1 += __shfl_down(s1, 2, 4); s1 += __shfl_down(s1, 1, 4);
  s2 += __shfl_down(s2, 2, 4); s2 += __shfl_down(s2, 1, 4);
  sl += __shfl_down(sl, 2, 4); sl += __shfl_down(sl, 1, 4);
  if (q == 0) {
    float L = fmaxf(sl, 1.f);
    float mu = s1 / L;
    float var = s2 / L - mu * mu;
    mean[(size_t)b * C + c0 + row] = mu;
    stdv[(size_t)b * C + c0 + row] = sqrtf(fmaxf(var, EPSF));
  }
}

// ---------------- K2: bias2[b,d] = attn_b[d] + w[d,C:2C].mean + w[d,2C:3C].std (fp32)
__global__ __launch_bounds__(256) void k_bias2(
    const float* __restrict__ attn_w, const float* __restrict__ attn_b,
    const float* __restrict__ mean, const float* __restrict__ stdv,
    float* __restrict__ bias2, int C, int D) {
  int bd = blockIdx.x;
  int b = bd / D;
  int d = bd % D;
  const float* wr = attn_w + (size_t)d * 3 * C;
  float s = 0.f;
  for (int c = threadIdx.x; c < C; c += 256)
    s += wr[C + c] * mean[(size_t)b * C + c] + wr[2 * C + c] * stdv[(size_t)b * C + c];
  __shared__ float r[4];
  s = wred_sum(s);
  if ((threadIdx.x & 63) == 0) r[threadIdx.x >> 6] = s;
  __syncthreads();
  if (threadIdx.x == 0) bias2[bd] = attn_b[d] + r[0] + r[1] + r[2] + r[3];
}

// ---------------- K3: MFMA GEMM1 -> alphaT[b][t][d] = tanh(bias2 + sum_c xbT*awb)
__global__ __launch_bounds__(256) void k_gemm1(
    const unsigned short* __restrict__ xbT, const unsigned short* __restrict__ awb,
    const float* __restrict__ bias2, unsigned short* __restrict__ alphaT,
    int C, int T, int D) {
  int b = blockIdx.y;
  int t0 = blockIdx.x * 128;
  int tid = threadIdx.x;
  int w = tid >> 6, lane = tid & 63;
  int wt0 = (w >> 1) * 64, wd0 = (w & 1) * 64;
  int l15 = lane & 15, g = lane >> 4;
  __shared__ unsigned short As[128][72];  // [t][c] pitch 144B -> 2-way (free)
  __shared__ unsigned short Bs[128][72];  // [d][c]
  f32x4 acc[4][4];
#pragma unroll
  for (int i = 0; i < 4; i++)
#pragma unroll
    for (int j = 0; j < 4; j++) acc[i][j] = (f32x4){0.f, 0.f, 0.f, 0.f};

  int srow = tid >> 1, h = tid & 1;
  for (int c0 = 0; c0 < C; c0 += 64) {
    __syncthreads();
    {
      bool ok = (t0 + srow) < T;
      size_t baseA = ((size_t)b * T + t0 + srow) * C + c0 + h * 32;
      size_t baseB = (size_t)srow * C + c0 + h * 32;
#pragma unroll
      for (int qq = 0; qq < 4; qq++) {
        short8 v = {};
        if (ok) v = *reinterpret_cast<const short8*>(&xbT[baseA + qq * 8]);
        *reinterpret_cast<short8*>(&As[srow][h * 32 + qq * 8]) = v;
        *reinterpret_cast<short8*>(&Bs[srow][h * 32 + qq * 8]) =
            *reinterpret_cast<const short8*>(&awb[baseB + qq * 8]);
      }
    }
    __syncthreads();
#pragma unroll
    for (int ks = 0; ks < 2; ks++) {
      short8 a[4], bb[4];
#pragma unroll
      for (int tf = 0; tf < 4; tf++)
        a[tf] = *reinterpret_cast<const short8*>(&As[wt0 + tf * 16 + l15][ks * 32 + g * 8]);
#pragma unroll
      for (int df = 0; df < 4; df++)
        bb[df] = *reinterpret_cast<const short8*>(&Bs[wd0 + df * 16 + l15][ks * 32 + g * 8]);
#pragma unroll
      for (int tf = 0; tf < 4; tf++)
#pragma unroll
        for (int df = 0; df < 4; df++)
          acc[tf][df] = __builtin_amdgcn_mfma_f32_16x16x32_bf16(a[tf], bb[df], acc[tf][df], 0, 0, 0);
    }
  }
#pragma unroll
  for (int df = 0; df < 4; df++) {
    int d = wd0 + df * 16 + l15;
    float bias = bias2[(size_t)b * D + d];
#pragma unroll
    for (int tf = 0; tf < 4; tf++)
#pragma unroll
      for (int r = 0; r < 4; r++) {
        int t = t0 + wt0 + tf * 16 + g * 4 + r;
        if (t < T)
          alphaT[((size_t)b * T + t) * D + d] = f2bf(tanhf(bias + acc[tf][df][r]));
      }
  }
}

// ---------------- K4: fused MFMA GEMM2 + masked softmax (no max-sub) + pooled stats
__global__ __launch_bounds__(256) void k_pool2(
    const unsigned short* __restrict__ alphaT, const unsigned short* __restrict__ cwb,
    const float* __restrict__ ctx_b, const float* __restrict__ x,
    const int* __restrict__ mask, float* __restrict__ out,
    int C, int T, int D) {
  int b = blockIdx.y;
  int c0 = blockIdx.x * 64;
  int tid = threadIdx.x;
  int w = tid >> 6, lane = tid & 63, l15 = lane & 15, g = lane >> 4;
  __shared__ unsigned short Bl[128][136];  // [t][d] pitch 272B -> 2-way (free)
  __shared__ unsigned short Wl[64][136];   // [c][d]
  {
    int c = tid >> 2, q = tid & 3;
    size_t src = (size_t)(c0 + c) * D + q * 32;
#pragma unroll
    for (int m = 0; m < 4; m++)
      *reinterpret_cast<short8*>(&Wl[c][q * 32 + m * 8]) =
          *reinterpret_cast<const short8*>(&cwb[src + m * 8]);
  }
  __syncthreads();
  short8 a[4];
#pragma unroll
  for (int ks = 0; ks < 4; ks++)
    a[ks] = *reinterpret_cast<const short8*>(&Wl[w * 16 + l15][ks * 32 + g * 8]);
  int cbase = c0 + w * 16 + g * 4;
  float cb[4];
#pragma unroll
  for (int r = 0; r < 4; r++) cb[r] = ctx_b[cbase + r];
  float S0[4] = {0.f, 0.f, 0.f, 0.f};
  float S1[4] = {0.f, 0.f, 0.f, 0.f};
  float S2[4] = {0.f, 0.f, 0.f, 0.f};

  int srow = tid >> 1, hh = tid & 1;
  const int* mr = mask + (size_t)b * T;
  for (int t0 = 0; t0 < T; t0 += 128) {
    __syncthreads();
    {
      bool ok = (t0 + srow) < T;
      size_t base = ((size_t)b * T + t0 + srow) * D + hh * 64;
#pragma unroll
      for (int qq = 0; qq < 8; qq++) {
        short8 v = {};
        if (ok) v = *reinterpret_cast<const short8*>(&alphaT[base + qq * 8]);
        *reinterpret_cast<short8*>(&Bl[srow][hh * 64 + qq * 8]) = v;
      }
    }
    __syncthreads();
#pragma unroll
    for (int tf = 0; tf < 8; tf++) {
      f32x4 p = (f32x4){0.f, 0.f, 0.f, 0.f};
#pragma unroll
      for (int ks = 0; ks < 4; ks++) {
        short8 bb = *reinterpret_cast<const short8*>(&Bl[tf * 16 + l15][ks * 32 + g * 8]);
        p = __builtin_amdgcn_mfma_f32_16x16x32_bf16(a[ks], bb, p, 0, 0, 0);
      }
      int t = t0 + tf * 16 + l15;
      bool valid = (t < T) && (mr[t < T ? t : 0] != 0);
#pragma unroll
      for (int r = 0; r < 4; r++) {
        float e = 0.f, xv = 0.f;
        if (valid) {
          e = __expf(p[r] + cb[r]);   // logits bounded -> no max-subtraction needed
          xv = x[((size_t)b * C + cbase + r) * T + t];
        }
        S0[r] += e; S1[r] += e * xv; S2[r] += e * xv * xv;
      }
    }
  }
#pragma unroll
  for (int r = 0; r < 4; r++) {
#pragma unroll
    for (int o = 1; o < 16; o <<= 1) {
      S0[r] += __shfl_xor(S0[r], o, 16);
      S1[r] += __shfl_xor(S1[r], o, 16);
      S2[r] += __shfl_xor(S2[r], o, 16);
    }
  }
  if (l15 == 0) {
#pragma unroll
    for (int r = 0; r < 4; r++) {
      float pm = S1[r] / S0[r];
      float var = S2[r] / S0[r] - pm * pm;
      out[(size_t)b * 2 * C + cbase + r] = pm;
      out[(size_t)b * 2 * C + C + cbase + r] = sqrtf(fmaxf(var, EPSF));
    }
  }
}

extern "C" void kernel_launch(void* const* d_in, const int* in_sizes, int n_in,
                              void* d_out, int out_size, void* d_ws, size_t ws_size,
                              hipStream_t stream) {
  const float* x = (const float*)d_in[0];
  const float* attn_w = (const float*)d_in[1];
  const float* attn_b = (const float*)d_in[2];
  const float* ctx_w = (const float*)d_in[3];
  const float* ctx_b = (const float*)d_in[4];
  const int* mask = (const int*)d_in[5];
  float* out = (float*)d_out;

  int D = in_sizes[2];         // 128
  int C = in_sizes[4];         // 512
  int B = out_size / (2 * C);  // 32
  int T = in_sizes[5] / B;     // 2000

  // workspace layout (~82.3 MB)
  unsigned short* awb = (unsigned short*)d_ws;        // D*C bf16
  unsigned short* cwb = awb + (size_t)D * C;          // C*D bf16
  float* mean = (float*)(cwb + (size_t)C * D);        // B*C
  float* stdv = mean + (size_t)B * C;                 // B*C
  float* bias2 = stdv + (size_t)B * C;                // B*D
  unsigned short* xbT = (unsigned short*)(bias2 + (size_t)B * D);  // B*T*C bf16
  unsigned short* alphaT = xbT + (size_t)B * T * C;                // B*T*D bf16

  k_convert<<<(2 * D * C + 255) / 256, 256, 0, stream>>>(attn_w, ctx_w, awb, cwb, C, D);
  k_ms_tr<<<dim3(C / 64, B), 256, 0, stream>>>(x, mask, mean, stdv, xbT, C, T);
  k_bias2<<<B * D, 256, 0, stream>>>(attn_w, attn_b, mean, stdv, bias2, C, D);
  k_gemm1<<<dim3((T + 127) / 128, B), 256, 0, stream>>>(xbT, awb, bias2, alphaT, C, T, D);
  k_pool2<<<dim3(C / 64, B), 256, 0, stream>>>(alphaT, cwb, ctx_b, x, mask, out, C, T, D);
}

// Round 3
// 158.058 us; speedup vs baseline: 2.5694x; 1.3182x over previous
//
#include <hip/hip_runtime.h>
#include <hip/hip_bf16.h>
#include <math.h>

#define EPSF 1e-8f
typedef __attribute__((ext_vector_type(8))) short short8;
typedef __attribute__((ext_vector_type(4))) float f32x4;

__device__ __forceinline__ float wred_sum(float v) {
#pragma unroll
  for (int o = 32; o > 0; o >>= 1) v += __shfl_down(v, o, 64);
  return v;
}

static __device__ __forceinline__ unsigned short f2bf(float f) {
  __hip_bfloat16 h = __float2bfloat16(f);
  return *reinterpret_cast<unsigned short*>(&h);
}

// ---------------- K0: weights -> bf16 (awb[d][c] from attn_w[:, :C]; cwb = ctx_w)
__global__ __launch_bounds__(256) void k_convert(
    const float* __restrict__ attn_w, const float* __restrict__ ctx_w,
    unsigned short* __restrict__ awb, unsigned short* __restrict__ cwb, int C, int D) {
  int i = blockIdx.x * 256 + threadIdx.x;
  int DC = D * C;
  if (i < DC) {
    int d = i / C, c = i % C;
    awb[i] = f2bf(attn_w[(size_t)d * 3 * C + c]);
  } else if (i < 2 * DC) {
    int j = i - DC;
    cwb[j] = f2bf(ctx_w[j]);
  }
}

// ---------------- K1: t-tiled masked partial sums + transpose x -> xbT[b][t][c] bf16
// grid (C/64, T/64 tiles, B); atomicAdd partial s1,s2 into sums[b*C+c][2]
__global__ __launch_bounds__(256) void k_ms_tr(
    const float* __restrict__ x, const int* __restrict__ mask,
    float* __restrict__ sums, unsigned short* __restrict__ xbT, int C, int T) {
  int b = blockIdx.z, c0 = blockIdx.x * 64, t0 = blockIdx.y * 64;
  int tid = threadIdx.x;
  int row = tid >> 2, q = tid & 3;
  __shared__ float Xs[64][65];
  const float* xr = x + ((size_t)b * C + c0 + row) * T;
  const int* mr = mask + (size_t)b * T;
  float s1 = 0.f, s2 = 0.f;

#pragma unroll
  for (int ss = 0; ss < 4; ss++) {
    int cc = q + 4 * ss;
    int t = t0 + cc * 4;
    float4 v;
    float mv[4];
    if (t + 3 < T) {
      v = *reinterpret_cast<const float4*>(&xr[t]);
      int4 mm = *reinterpret_cast<const int4*>(&mr[t]);
      mv[0] = (float)mm.x; mv[1] = (float)mm.y; mv[2] = (float)mm.z; mv[3] = (float)mm.w;
    } else {
      v.x = (t < T) ? xr[t] : 0.f;     mv[0] = (t < T) ? (float)mr[t] : 0.f;
      v.y = (t+1 < T) ? xr[t+1] : 0.f; mv[1] = (t+1 < T) ? (float)mr[t+1] : 0.f;
      v.z = (t+2 < T) ? xr[t+2] : 0.f; mv[2] = (t+2 < T) ? (float)mr[t+2] : 0.f;
      v.w = (t+3 < T) ? xr[t+3] : 0.f; mv[3] = (t+3 < T) ? (float)mr[t+3] : 0.f;
    }
    s1 += mv[0]*v.x + mv[1]*v.y + mv[2]*v.z + mv[3]*v.w;
    s2 += mv[0]*v.x*v.x + mv[1]*v.y*v.y + mv[2]*v.z*v.z + mv[3]*v.w*v.w;
    int tl = cc * 4;
    Xs[row][tl+0] = v.x; Xs[row][tl+1] = v.y; Xs[row][tl+2] = v.z; Xs[row][tl+3] = v.w;
  }
  __syncthreads();
  // transpose write: thread (trow, q) writes 16 c's of xbT row t0+trow
  {
    int trow = tid >> 2;
    int t = t0 + trow;
    if (t < T) {
      unsigned short buf[16];
#pragma unroll
      for (int m = 0; m < 16; m++) buf[m] = f2bf(Xs[q * 16 + m][trow]);
      unsigned short* dst = &xbT[((size_t)b * T + t) * C + c0 + q * 16];
      *reinterpret_cast<short8*>(dst) = *reinterpret_cast<short8*>(&buf[0]);
      *reinterpret_cast<short8*>(dst + 8) = *reinterpret_cast<short8*>(&buf[8]);
    }
  }
  // reduce the 4 lanes sharing a c-row, then atomic into global accumulator
  s1 += __shfl_down(s1, 2, 4); s1 += __shfl_down(s1, 1, 4);
  s2 += __shfl_down(s2, 2, 4); s2 += __shfl_down(s2, 1, 4);
  if (q == 0) {
    float* sp = &sums[((size_t)b * C + c0 + row) * 2];
    atomicAdd(sp, s1);
    atomicAdd(sp + 1, s2);
  }
}

// ---------------- K1b: finalize mean/std from sums + mask lengths
__global__ __launch_bounds__(256) void k_ms_fin(
    const float* __restrict__ sums, const int* __restrict__ mask,
    float* __restrict__ mean, float* __restrict__ stdv, int C, int T) {
  int b = blockIdx.x;
  int tid = threadIdx.x;
  const int* mr = mask + (size_t)b * T;
  float sl = 0.f;
  for (int t = tid; t < T; t += 256) sl += (float)mr[t];
  __shared__ float rl[4];
  sl = wred_sum(sl);
  if ((tid & 63) == 0) rl[tid >> 6] = sl;
  __syncthreads();
  float L = fmaxf(rl[0] + rl[1] + rl[2] + rl[3], 1.f);
  for (int c = tid; c < C; c += 256) {
    float s1 = sums[((size_t)b * C + c) * 2];
    float s2 = sums[((size_t)b * C + c) * 2 + 1];
    float mu = s1 / L;
    float var = s2 / L - mu * mu;
    mean[(size_t)b * C + c] = mu;
    stdv[(size_t)b * C + c] = sqrtf(fmaxf(var, EPSF));
  }
}

// ---------------- K2: bias2[b,d] = attn_b[d] + w[d,C:2C].mean + w[d,2C:3C].std (fp32)
__global__ __launch_bounds__(256) void k_bias2(
    const float* __restrict__ attn_w, const float* __restrict__ attn_b,
    const float* __restrict__ mean, const float* __restrict__ stdv,
    float* __restrict__ bias2, int C, int D) {
  int bd = blockIdx.x;
  int b = bd / D;
  int d = bd % D;
  const float* wr = attn_w + (size_t)d * 3 * C;
  float s = 0.f;
  for (int c = threadIdx.x; c < C; c += 256)
    s += wr[C + c] * mean[(size_t)b * C + c] + wr[2 * C + c] * stdv[(size_t)b * C + c];
  __shared__ float r[4];
  s = wred_sum(s);
  if ((threadIdx.x & 63) == 0) r[threadIdx.x >> 6] = s;
  __syncthreads();
  if (threadIdx.x == 0) bias2[bd] = attn_b[d] + r[0] + r[1] + r[2] + r[3];
}

// ---------------- K3: MFMA GEMM1 -> alphaT[b][t][d] = tanh(bias2 + sum_c xbT*awb)
__global__ __launch_bounds__(256) void k_gemm1(
    const unsigned short* __restrict__ xbT, const unsigned short* __restrict__ awb,
    const float* __restrict__ bias2, unsigned short* __restrict__ alphaT,
    int C, int T, int D) {
  int b = blockIdx.y;
  int t0 = blockIdx.x * 128;
  int tid = threadIdx.x;
  int w = tid >> 6, lane = tid & 63;
  int wt0 = (w >> 1) * 64, wd0 = (w & 1) * 64;
  int l15 = lane & 15, g = lane >> 4;
  __shared__ unsigned short As[128][72];  // [t][c] pitch 144B -> 2-way (free)
  __shared__ unsigned short Bs[128][72];  // [d][c]
  f32x4 acc[4][4];
#pragma unroll
  for (int i = 0; i < 4; i++)
#pragma unroll
    for (int j = 0; j < 4; j++) acc[i][j] = (f32x4){0.f, 0.f, 0.f, 0.f};

  int srow = tid >> 1, h = tid & 1;
  for (int c0 = 0; c0 < C; c0 += 64) {
    __syncthreads();
    {
      bool ok = (t0 + srow) < T;
      size_t baseA = ((size_t)b * T + t0 + srow) * C + c0 + h * 32;
      size_t baseB = (size_t)srow * C + c0 + h * 32;
#pragma unroll
      for (int qq = 0; qq < 4; qq++) {
        short8 v = {};
        if (ok) v = *reinterpret_cast<const short8*>(&xbT[baseA + qq * 8]);
        *reinterpret_cast<short8*>(&As[srow][h * 32 + qq * 8]) = v;
        *reinterpret_cast<short8*>(&Bs[srow][h * 32 + qq * 8]) =
            *reinterpret_cast<const short8*>(&awb[baseB + qq * 8]);
      }
    }
    __syncthreads();
#pragma unroll
    for (int ks = 0; ks < 2; ks++) {
      short8 a[4], bb[4];
#pragma unroll
      for (int tf = 0; tf < 4; tf++)
        a[tf] = *reinterpret_cast<const short8*>(&As[wt0 + tf * 16 + l15][ks * 32 + g * 8]);
#pragma unroll
      for (int df = 0; df < 4; df++)
        bb[df] = *reinterpret_cast<const short8*>(&Bs[wd0 + df * 16 + l15][ks * 32 + g * 8]);
#pragma unroll
      for (int tf = 0; tf < 4; tf++)
#pragma unroll
        for (int df = 0; df < 4; df++)
          acc[tf][df] = __builtin_amdgcn_mfma_f32_16x16x32_bf16(a[tf], bb[df], acc[tf][df], 0, 0, 0);
    }
  }
#pragma unroll
  for (int df = 0; df < 4; df++) {
    int d = wd0 + df * 16 + l15;
    float bias = bias2[(size_t)b * D + d];
#pragma unroll
    for (int tf = 0; tf < 4; tf++)
#pragma unroll
      for (int r = 0; r < 4; r++) {
        int t = t0 + wt0 + tf * 16 + g * 4 + r;
        if (t < T)
          alphaT[((size_t)b * T + t) * D + d] = f2bf(tanhf(bias + acc[tf][df][r]));
      }
  }
}

// ---------------- K4: t-tiled fused MFMA GEMM2 + masked exp + partial pooled sums
// grid (t-chunks of 256, C/64, B); atomicAdd partial S0/S1/S2 into Sacc[b*C+c][3]
__global__ __launch_bounds__(256) void k_pool2(
    const unsigned short* __restrict__ alphaT, const unsigned short* __restrict__ cwb,
    const float* __restrict__ ctx_b, const float* __restrict__ x,
    const int* __restrict__ mask, float* __restrict__ Sacc,
    int C, int T, int D) {
  int b = blockIdx.z;
  int c0 = blockIdx.y * 64;
  int ch0 = blockIdx.x * 256;
  int tid = threadIdx.x;
  int w = tid >> 6, lane = tid & 63, l15 = lane & 15, g = lane >> 4;
  __shared__ unsigned short Bl[128][136];  // [t][d] pitch 272B -> 2-way (free)

  // ctx_w fragments straight from global (L2-resident, 128 KB)
  short8 a[4];
#pragma unroll
  for (int ks = 0; ks < 4; ks++)
    a[ks] = *reinterpret_cast<const short8*>(
        &cwb[(size_t)(c0 + w * 16 + l15) * D + ks * 32 + g * 8]);
  int cbase = c0 + w * 16 + g * 4;
  float cb[4];
#pragma unroll
  for (int r = 0; r < 4; r++) cb[r] = ctx_b[cbase + r];
  float S0[4] = {0.f, 0.f, 0.f, 0.f};
  float S1[4] = {0.f, 0.f, 0.f, 0.f};
  float S2[4] = {0.f, 0.f, 0.f, 0.f};

  int srow = tid >> 1, hh = tid & 1;
  const int* mr = mask + (size_t)b * T;
#pragma unroll
  for (int tt = 0; tt < 2; tt++) {
    int t0 = ch0 + tt * 128;
    if (t0 >= T) break;  // uniform across block
    __syncthreads();
    {
      bool ok = (t0 + srow) < T;
      size_t base = ((size_t)b * T + t0 + srow) * D + hh * 64;
#pragma unroll
      for (int qq = 0; qq < 8; qq++) {
        short8 v = {};
        if (ok) v = *reinterpret_cast<const short8*>(&alphaT[base + qq * 8]);
        *reinterpret_cast<short8*>(&Bl[srow][hh * 64 + qq * 8]) = v;
      }
    }
    __syncthreads();
#pragma unroll
    for (int tf = 0; tf < 8; tf++) {
      f32x4 p = (f32x4){0.f, 0.f, 0.f, 0.f};
#pragma unroll
      for (int ks = 0; ks < 4; ks++) {
        short8 bb = *reinterpret_cast<const short8*>(&Bl[tf * 16 + l15][ks * 32 + g * 8]);
        p = __builtin_amdgcn_mfma_f32_16x16x32_bf16(a[ks], bb, p, 0, 0, 0);
      }
      int t = t0 + tf * 16 + l15;
      bool valid = (t < T) && (mr[t < T ? t : 0] != 0);
#pragma unroll
      for (int r = 0; r < 4; r++) {
        float e = 0.f, xv = 0.f;
        if (valid) {
          e = __expf(p[r] + cb[r]);   // logits bounded -> no max-subtraction needed
          xv = x[((size_t)b * C + cbase + r) * T + t];
        }
        S0[r] += e; S1[r] += e * xv; S2[r] += e * xv * xv;
      }
    }
  }
#pragma unroll
  for (int r = 0; r < 4; r++) {
#pragma unroll
    for (int o = 1; o < 16; o <<= 1) {
      S0[r] += __shfl_xor(S0[r], o, 16);
      S1[r] += __shfl_xor(S1[r], o, 16);
      S2[r] += __shfl_xor(S2[r], o, 16);
    }
  }
  if (l15 == 0) {
#pragma unroll
    for (int r = 0; r < 4; r++) {
      float* sp = &Sacc[((size_t)b * C + cbase + r) * 3];
      atomicAdd(sp, S0[r]);
      atomicAdd(sp + 1, S1[r]);
      atomicAdd(sp + 2, S2[r]);
    }
  }
}

// ---------------- K5: finalize pooled mean/std
__global__ __launch_bounds__(256) void k_out(
    const float* __restrict__ Sacc, float* __restrict__ out, int C) {
  int b = blockIdx.x;
  for (int c = threadIdx.x; c < C; c += 256) {
    float S0 = Sacc[((size_t)b * C + c) * 3];
    float S1 = Sacc[((size_t)b * C + c) * 3 + 1];
    float S2 = Sacc[((size_t)b * C + c) * 3 + 2];
    float pm = S1 / S0;
    float var = S2 / S0 - pm * pm;
    out[(size_t)b * 2 * C + c] = pm;
    out[(size_t)b * 2 * C + C + c] = sqrtf(fmaxf(var, EPSF));
  }
}

extern "C" void kernel_launch(void* const* d_in, const int* in_sizes, int n_in,
                              void* d_out, int out_size, void* d_ws, size_t ws_size,
                              hipStream_t stream) {
  const float* x = (const float*)d_in[0];
  const float* attn_w = (const float*)d_in[1];
  const float* attn_b = (const float*)d_in[2];
  const float* ctx_w = (const float*)d_in[3];
  const float* ctx_b = (const float*)d_in[4];
  const int* mask = (const int*)d_in[5];
  float* out = (float*)d_out;

  int D = in_sizes[2];         // 128
  int C = in_sizes[4];         // 512
  int B = out_size / (2 * C);  // 32
  int T = in_sizes[5] / B;     // 2000

  // workspace layout (~82.7 MB)
  unsigned short* awb = (unsigned short*)d_ws;        // D*C bf16
  unsigned short* cwb = awb + (size_t)D * C;          // C*D bf16
  float* mean = (float*)(cwb + (size_t)C * D);        // B*C
  float* stdv = mean + (size_t)B * C;                 // B*C
  float* bias2 = stdv + (size_t)B * C;                // B*D
  float* sums = bias2 + (size_t)B * D;                // B*C*2 (zeroed)
  float* Sacc = sums + (size_t)B * C * 2;             // B*C*3 (zeroed)
  unsigned short* xbT = (unsigned short*)(Sacc + (size_t)B * C * 3);  // B*T*C bf16
  unsigned short* alphaT = xbT + (size_t)B * T * C;                   // B*T*D bf16

  hipMemsetAsync(sums, 0, (size_t)B * C * 5 * sizeof(float), stream);
  k_convert<<<(2 * D * C + 255) / 256, 256, 0, stream>>>(attn_w, ctx_w, awb, cwb, C, D);
  k_ms_tr<<<dim3(C / 64, (T + 63) / 64, B), 256, 0, stream>>>(x, mask, sums, xbT, C, T);
  k_ms_fin<<<B, 256, 0, stream>>>(sums, mask, mean, stdv, C, T);
  k_bias2<<<B * D, 256, 0, stream>>>(attn_w, attn_b, mean, stdv, bias2, C, D);
  k_gemm1<<<dim3((T + 127) / 128, B), 256, 0, stream>>>(xbT, awb, bias2, alphaT, C, T, D);
  k_pool2<<<dim3((T + 255) / 256, C / 64, B), 256, 0, stream>>>(
      alphaT, cwb, ctx_b, x, mask, Sacc, C, T, D);
  k_out<<<B, 256, 0, stream>>>(Sacc, out, C);
}